// Round 4
// baseline (2456.510 us; speedup 1.0000x reference)
//
#include <hip/hip_runtime.h>
#include <cstdint>
#include <math.h>
#include <float.h>

// Problem constants (fixed by setup_inputs)
#define N_Q   4
#define NROWS 32768      // 16*2048
#define EDIM  256
#define NE    2048

// Tiling
#define TM 32            // rows per block (fp32 residual resident in LDS)
#define TN 128           // codes per chunk
#define BK 16            // k-chunk for B staging
#define NTHREADS 256

#define RES_STRIDE 260   // floats; 1040 B rows -> 16B aligned
#define BT_STRIDE  132   // floats; 528 B rows -> 16B aligned

// Output layout: z_q (8388608) | loss (1) | indices (131072), all fp32
#define ZQ_SIZE  (NROWS * EDIM)
#define LOSS_OFF ZQ_SIZE
#define IDX_OFF  (ZQ_SIZE + 1)

// ---- numpy pairwise fp32 sum emulation (n=256 = block128 + block128) ----
// numpy materializes flat*flat first (each square rounded), then pairwise-sums
// with the scalar 8-accumulator kernel. fp contract must be off so v*v is
// rounded before the add.
__device__ __forceinline__ float np_block128_sq(const float* __restrict__ p) {
    #pragma clang fp contract(off)
    float r[8];
    #pragma unroll
    for (int j = 0; j < 8; ++j) { float v = p[j]; r[j] = v * v; }
    for (int i = 8; i < 128; i += 8) {
        #pragma unroll
        for (int j = 0; j < 8; ++j) { float v = p[i + j]; float sq = v * v; r[j] = r[j] + sq; }
    }
    return ((r[0] + r[1]) + (r[2] + r[3])) + ((r[4] + r[5]) + (r[6] + r[7]));
}

__device__ __forceinline__ float np_sumsq256(const float* __restrict__ p) {
    #pragma clang fp contract(off)
    float a = np_block128_sq(p);
    float b = np_block128_sq(p + 128);
    return a + b;
}

__global__ __launch_bounds__(256) void wsq_kernel(const float* __restrict__ W,
                                                  float* __restrict__ wsq32) {
    // one wave per codebook row; 8192 rows total
    __shared__ float rowbuf[4][EDIM];
    int wv   = threadIdx.x >> 6;
    int row  = blockIdx.x * 4 + wv;
    int lane = threadIdx.x & 63;
    float4 v = ((const float4*)(W + (size_t)row * EDIM))[lane];
    *(float4*)&rowbuf[wv][lane * 4] = v;
    __syncthreads();
    if (lane == 0) wsq32[row] = np_sumsq256(rowbuf[wv]);   // numpy-emulated fp32
}

__global__ __launch_bounds__(256, 2) void rvq_main(const float* __restrict__ z,
                                                   const float* __restrict__ W,
                                                   const float* __restrict__ wsq32,
                                                   float* __restrict__ out,
                                                   float* __restrict__ loss_partial) {
    __shared__ float resd[TM * RES_STRIDE];     // 33280 B: fp32 residual (numpy chain)
    __shared__ float btbuf[BK * BT_STRIDE];     // 8448 B
    __shared__ float srow[TM];                  // per-row ||residual||^2, numpy-emulated
    __shared__ int   rowi1[TM];
    __shared__ float wavesum[4];

    const int tid  = threadIdx.x;
    const int tx   = tid & 31;   // 32 groups x 4 codes = 128 codes
    const int ty   = tid >> 5;   // 8 groups x 4 rows = 32 rows
    const int row0 = blockIdx.x * TM;

    // ---- load z tile into LDS residual ----
    for (int q = tid; q < TM * EDIM / 4; q += NTHREADS) {
        int r = q >> 6;          // 64 float4 per row
        int c = q & 63;
        float4 v = ((const float4*)z)[(size_t)(row0 + r) * (EDIM / 4) + c];
        *(float4*)&resd[r * RES_STRIDE + c * 4] = v;
    }

    float lsum = 0.f;

    for (int k = 0; k < N_Q; ++k) {
        const float* Wk   = W + (size_t)k * NE * EDIM;
        const float* wsqk = wsq32 + k * NE;

        __syncthreads();            // residual stable (also covers initial load)
        // ---- per-row S = numpy-emulated fp32 sum of squares of residual ----
        if (tid < TM) srow[tid] = np_sumsq256(&resd[tid * RES_STRIDE]);
        __syncthreads();

        const float Sr[4] = {srow[ty * 4 + 0], srow[ty * 4 + 1],
                             srow[ty * 4 + 2], srow[ty * 4 + 3]};

        float m1[4];
        int   i1[4];
        #pragma unroll
        for (int i = 0; i < 4; ++i) { m1[i] = INFINITY; i1[i] = 0; }

        for (int cc = 0; cc < NE; cc += TN) {
            float acc[4][4];
            #pragma unroll
            for (int i = 0; i < 4; ++i)
                #pragma unroll
                for (int j = 0; j < 4; ++j) acc[i][j] = 0.f;

            for (int kc = 0; kc < EDIM; kc += BK) {
                __syncthreads();   // btbuf free to overwrite
                // stage B tile transposed: btbuf[d][c] = Wk[cc+c][kc+d]
                {
                    int q = tid;
                    #pragma unroll
                    for (int it = 0; it < 2; ++it, q += NTHREADS) {
                        int c  = q >> 2;   // 0..127
                        int dq = q & 3;    // 0..3 (float4 along d)
                        float4 v = *(const float4*)(Wk + (size_t)(cc + c) * EDIM + kc + dq * 4);
                        int d0 = dq * 4;
                        btbuf[(d0 + 0) * BT_STRIDE + c] = v.x;
                        btbuf[(d0 + 1) * BT_STRIDE + c] = v.y;
                        btbuf[(d0 + 2) * BT_STRIDE + c] = v.z;
                        btbuf[(d0 + 3) * BT_STRIDE + c] = v.w;
                    }
                }
                __syncthreads();
                // micro-kernel: 4 rows x 4 codes. Each acc[i][j] is ONE
                // sequential fmaf chain in ascending k across all kc chunks —
                // bit-identical to OpenBLAS sgemm's per-element FMA chain.
                #pragma unroll
                for (int dd = 0; dd < BK; dd += 4) {
                    float4 av[4], bv[4];
                    #pragma unroll
                    for (int i = 0; i < 4; ++i)
                        av[i] = *(const float4*)&resd[(ty * 4 + i) * RES_STRIDE + kc + dd];
                    #pragma unroll
                    for (int u = 0; u < 4; ++u)
                        bv[u] = *(const float4*)&btbuf[(dd + u) * BT_STRIDE + tx * 4];
                    #pragma unroll
                    for (int i = 0; i < 4; ++i) {
                        const float a0 = av[i].x, a1 = av[i].y, a2 = av[i].z, a3 = av[i].w;
                        acc[i][0] = fmaf(a0, bv[0].x, acc[i][0]);
                        acc[i][1] = fmaf(a0, bv[0].y, acc[i][1]);
                        acc[i][2] = fmaf(a0, bv[0].z, acc[i][2]);
                        acc[i][3] = fmaf(a0, bv[0].w, acc[i][3]);
                        acc[i][0] = fmaf(a1, bv[1].x, acc[i][0]);
                        acc[i][1] = fmaf(a1, bv[1].y, acc[i][1]);
                        acc[i][2] = fmaf(a1, bv[1].z, acc[i][2]);
                        acc[i][3] = fmaf(a1, bv[1].w, acc[i][3]);
                        acc[i][0] = fmaf(a2, bv[2].x, acc[i][0]);
                        acc[i][1] = fmaf(a2, bv[2].y, acc[i][1]);
                        acc[i][2] = fmaf(a2, bv[2].z, acc[i][2]);
                        acc[i][3] = fmaf(a2, bv[2].w, acc[i][3]);
                        acc[i][0] = fmaf(a3, bv[3].x, acc[i][0]);
                        acc[i][1] = fmaf(a3, bv[3].y, acc[i][1]);
                        acc[i][2] = fmaf(a3, bv[3].z, acc[i][2]);
                        acc[i][3] = fmaf(a3, bv[3].w, acc[i][3]);
                    }
                }
            }

            // fold chunk into running (min1, idx1) on REFERENCE-EMULATED values:
            //   d = fp32( fp32(S - 2*G) + Wsq )   (2*G exact; S,Wsq numpy-emulated;
            //   G = the sequential fmaf chain above). Strict < + ascending code
            //   order per thread = numpy first-occurrence tie-break.
            #pragma unroll
            for (int j = 0; j < 4; ++j) {
                int cg = cc + tx * 4 + j;
                float wq = wsqk[cg];
                #pragma unroll
                for (int i = 0; i < 4; ++i) {
                    float t = Sr[i] - 2.0f * acc[i][j];   // 2*acc exact; fma-fusion safe
                    float d = t + wq;
                    if (d < m1[i]) { m1[i] = d; i1[i] = cg; }
                }
            }
        }

        // ---- cross-lane argmin reduce over the 32 tx lanes (butterfly) ----
        #pragma unroll
        for (int i = 0; i < 4; ++i) {
            float a1 = m1[i];
            int   ai = i1[i];
            #pragma unroll
            for (int mask = 1; mask < 32; mask <<= 1) {
                float b1 = __shfl_xor(a1, mask, 32);
                int   bi = __shfl_xor(ai, mask, 32);
                if (b1 < a1 || (b1 == a1 && bi < ai)) { a1 = b1; ai = bi; }
            }
            if (tx == 0) rowi1[ty * 4 + i] = ai;
        }
        __syncthreads();

        if (tid < TM)
            out[IDX_OFF + (size_t)(row0 + tid) * N_Q + k] = (float)rowi1[tid];

        // ---- residual update (plain fp32, matches numpy elementwise) + loss ----
        {
            #pragma clang fp contract(off)
            const int d = tid;
            for (int r = 0; r < TM; ++r) {
                float w  = Wk[(size_t)rowi1[r] * EDIM + d];
                float nv = resd[r * RES_STRIDE + d] - w;
                resd[r * RES_STRIDE + d] = nv;
                lsum = fmaf(nv, nv, lsum);   // loss threshold is loose
            }
        }
        __syncthreads();
    }

    // ---- write z_q = z - residual_final ----
    for (int q = tid; q < TM * EDIM / 4; q += NTHREADS) {
        int r = q >> 6;
        int c = q & 63;
        float4 zv = ((const float4*)z)[(size_t)(row0 + r) * (EDIM / 4) + c];
        float4 rv = *(const float4*)&resd[r * RES_STRIDE + c * 4];
        float4 o;
        o.x = zv.x - rv.x; o.y = zv.y - rv.y; o.z = zv.z - rv.z; o.w = zv.w - rv.w;
        ((float4*)out)[(size_t)(row0 + r) * (EDIM / 4) + c] = o;
    }

    // ---- per-block loss partial ----
    #pragma unroll
    for (int off = 32; off > 0; off >>= 1) lsum += __shfl_down(lsum, off, 64);
    if ((tid & 63) == 0) wavesum[tid >> 6] = lsum;
    __syncthreads();
    if (tid == 0)
        loss_partial[blockIdx.x] = wavesum[0] + wavesum[1] + wavesum[2] + wavesum[3];
}

__global__ __launch_bounds__(256) void loss_reduce(const float* __restrict__ partial,
                                                   float* __restrict__ out) {
    __shared__ float sh[256];
    int t = threadIdx.x;
    sh[t] = partial[t] + partial[t + 256] + partial[t + 512] + partial[t + 768];
    __syncthreads();
    for (int off = 128; off > 0; off >>= 1) {
        if (t < off) sh[t] += sh[t + off];
        __syncthreads();
    }
    if (t == 0)
        out[LOSS_OFF] = sh[0] * (1.25f / ((float)N_Q * (float)NROWS * (float)EDIM));
}

extern "C" void kernel_launch(void* const* d_in, const int* in_sizes, int n_in,
                              void* d_out, int out_size, void* d_ws, size_t ws_size,
                              hipStream_t stream) {
    const float* z = (const float*)d_in[0];   // [16,2048,256]
    const float* W = (const float*)d_in[1];   // [4,2048,256]
    float* out = (float*)d_out;

    // workspace layout (floats): wsq32 [8192] | partial [1024]
    float* wsq32   = (float*)d_ws;
    float* partial = wsq32 + 8192;

    hipLaunchKernelGGL(wsq_kernel, dim3(NE * N_Q / 4), dim3(NTHREADS), 0, stream,
                       W, wsq32);
    hipLaunchKernelGGL(rvq_main, dim3(NROWS / TM), dim3(NTHREADS), 0, stream,
                       z, W, wsq32, out, partial);
    hipLaunchKernelGGL(loss_reduce, dim3(1), dim3(NTHREADS), 0, stream, partial, out);
}

// Round 5
// 1339.384 us; speedup vs baseline: 1.8341x; 1.8341x over previous
//
#include <hip/hip_runtime.h>
#include <cstdint>
#include <math.h>
#include <float.h>

// Problem constants
#define N_Q   4
#define NROWS 32768
#define EDIM  256
#define NE    2048
#define NCT   128          // code tiles of 16 codes
#define TM    128          // rows per block (4 waves x 32 rows)
#define NTHREADS 256

// Output layout: z_q | loss | indices (fp32)
#define ZQ_SIZE  (NROWS * EDIM)
#define LOSS_OFF ZQ_SIZE
#define IDX_OFF  (ZQ_SIZE + 1)

// approx-vs-chain dist error worst-case ~1e-4; TAU gives >8x margin
#define TAU 1e-3f

typedef __attribute__((ext_vector_type(8))) __bf16 bf16x8;
typedef __attribute__((ext_vector_type(4))) float  f32x4;

union BF8 { unsigned short u[8]; bf16x8 v; };

__device__ __forceinline__ unsigned short f2bf_rne(float f) {
    unsigned int u = __float_as_uint(f);
    unsigned int r = (u + 0x7fffu + ((u >> 16) & 1u)) >> 16;
    return (unsigned short)r;
}
__device__ __forceinline__ float bf2f(unsigned short s) {
    return __uint_as_float(((unsigned int)s) << 16);
}

// ---- numpy pairwise fp32 sum-of-squares emulation (256 = 128 + 128) ----
__device__ __forceinline__ float np_block128_sq(const float* __restrict__ p) {
    #pragma clang fp contract(off)
    float r[8];
    #pragma unroll
    for (int j = 0; j < 8; ++j) { float v = p[j]; r[j] = v * v; }
    for (int i = 8; i < 128; i += 8) {
        #pragma unroll
        for (int j = 0; j < 8; ++j) { float v = p[i + j]; float sq = v * v; r[j] = r[j] + sq; }
    }
    return ((r[0] + r[1]) + (r[2] + r[3])) + ((r[4] + r[5]) + (r[6] + r[7]));
}
__device__ __forceinline__ float np_sumsq256(const float* __restrict__ p) {
    #pragma clang fp contract(off)
    float a = np_block128_sq(p);
    float b = np_block128_sq(p + 128);
    return a + b;
}

__global__ __launch_bounds__(256) void wsq_kernel(const float* __restrict__ W,
                                                  float* __restrict__ wsq32) {
    __shared__ float rowbuf[4][EDIM];
    int wv   = threadIdx.x >> 6;
    int row  = blockIdx.x * 4 + wv;
    int lane = threadIdx.x & 63;
    float4 v = ((const float4*)(W + (size_t)row * EDIM))[lane];
    *(float4*)&rowbuf[wv][lane * 4] = v;
    __syncthreads();
    if (lane == 0) wsq32[row] = np_sumsq256(rowbuf[wv]);
}

// Pre-split W into bf16 hi/lo, swizzled into MFMA B-frag blocks:
// whl layout (shorts): chunk = ((q*128+ct)*8+ks)*2+h ; within chunk: lane*8+j
// value = bfpart( W[q][ct*16 + (lane&15)][ks*32 + (lane>>4)*8 + j] )
__global__ __launch_bounds__(256) void whl_kernel(const float* __restrict__ W,
                                                  short* __restrict__ whl) {
    int gid  = blockIdx.x * 256 + threadIdx.x;
    int lane = gid & 63;
    int grp  = gid >> 6;                 // (q*128+ct)*8+ks, 4096 total
    int ks   = grp & 7;
    int ctq  = grp >> 3;                 // q*128+ct
    int n = lane & 15, kq = lane >> 4;
    const float* src = W + (((size_t)(ctq * 16 + n)) << 8) + ks * 32 + kq * 8;
    float4 p0 = *(const float4*)src;
    float4 p1 = *(const float4*)(src + 4);
    float v[8] = {p0.x, p0.y, p0.z, p0.w, p1.x, p1.y, p1.z, p1.w};
    BF8 h, l;
    #pragma unroll
    for (int j = 0; j < 8; ++j) {
        float f = v[j];
        unsigned short hb = f2bf_rne(f);
        h.u[j] = hb;
        l.u[j] = f2bf_rne(f - bf2f(hb));
    }
    size_t base = ((size_t)grp << 10) + lane * 8;   // shorts
    *(bf16x8*)(whl + base)       = h.v;
    *(bf16x8*)(whl + base + 512) = l.v;
}

__global__ __launch_bounds__(256, 1) void rvq_main(
    const float* __restrict__ z, const float* __restrict__ W,
    const float* __restrict__ wsq32, const short* __restrict__ whl,
    float* __restrict__ resd_g, float* __restrict__ out,
    float* __restrict__ loss_partial)
{
    __shared__ __align__(16) short lds_b[2][16][512];  // 32 KB B-frag dbuf
    __shared__ float wsq_lds[NE];                      // 8 KB
    __shared__ float Srow[TM];
    __shared__ float rowm1[TM], rowm2[TM];
    __shared__ int   rowi1[TM], idx_s[TM];
    __shared__ int   rk_cnt, rk_list[TM];
    __shared__ float rrow_s[EDIM];
    __shared__ float red_f[NTHREADS];
    __shared__ int   red_i[NTHREADS];
    __shared__ float wavesum[4];

    const int tid  = threadIdx.x;
    const int wave = tid >> 6;
    const int lane = tid & 63;
    const int n    = lane & 15;
    const int kq   = lane >> 4;
    const int row0 = blockIdx.x * TM;
    const int rowg = row0 + wave * 32;

    // init: copy z -> residual (own rows only; no cross-block deps)
    for (int i = tid; i < TM * 64; i += NTHREADS) {
        int r = i >> 6, c = i & 63;
        ((float4*)resd_g)[(((size_t)(row0 + r)) << 6) + c] =
            ((const float4*)z)[(((size_t)(row0 + r)) << 6) + c];
    }

    float lsum = 0.f;

    for (int q = 0; q < N_Q; ++q) {
        const float* Wk   = W + (size_t)q * NE * EDIM;
        const short* whlq = whl + (size_t)q * NCT * 16 * 512;

        __syncthreads();   // residual stable; lds_b free
        if (tid == 0) rk_cnt = 0;
        for (int i = tid; i < NE / 4; i += NTHREADS)
            ((float4*)wsq_lds)[i] = ((const float4*)(wsq32 + q * NE))[i];
        {
            int r = tid >> 1, half = tid & 1;
            float s = np_block128_sq(resd_g + (((size_t)(row0 + r)) << 8) + half * 128);
            float s2 = __shfl_xor(s, 1, 64);
            if (half == 0) Srow[r] = s + s2;   // block0 + block1 (numpy order)
        }
        __syncthreads();

        // ---- A-frag conversion: 2 row-tiles x 8 k-steps, hi/lo resident ----
        bf16x8 ah[2][8], al[2][8];
        #pragma unroll
        for (int rt = 0; rt < 2; ++rt) {
            #pragma unroll
            for (int ks = 0; ks < 8; ++ks) {
                const float* rp = resd_g + (((size_t)(rowg + rt * 16 + n)) << 8) + ks * 32 + kq * 8;
                float4 p0 = *(const float4*)rp;
                float4 p1 = *(const float4*)(rp + 4);
                float v[8] = {p0.x, p0.y, p0.z, p0.w, p1.x, p1.y, p1.z, p1.w};
                BF8 h, l;
                #pragma unroll
                for (int j = 0; j < 8; ++j) {
                    float f = v[j];
                    unsigned short hb = f2bf_rne(f);
                    h.u[j] = hb;
                    l.u[j] = f2bf_rne(f - bf2f(hb));
                }
                ah[rt][ks] = h.v; al[rt][ks] = l.v;
            }
        }
        float sreg[2][4];
        #pragma unroll
        for (int rt = 0; rt < 2; ++rt)
            #pragma unroll
            for (int rg = 0; rg < 4; ++rg)
                sreg[rt][rg] = Srow[wave * 32 + rt * 16 + kq * 4 + rg];

        float m1[8], m2[8]; int i1[8];
        #pragma unroll
        for (int s = 0; s < 8; ++s) { m1[s] = INFINITY; m2[s] = INFINITY; i1[s] = 0; }

        // prologue: stage ct=0 into buf 0 (wave stages its 4 chunks)
        #pragma unroll
        for (int i = 0; i < 4; ++i) {
            int ch = wave * 4 + i;
            const short* gp = whlq + (((size_t)ch) << 9) + lane * 8;
            __builtin_amdgcn_global_load_lds(
                (const __attribute__((address_space(1))) void*)gp,
                (__attribute__((address_space(3))) void*)&lds_b[0][ch][0], 16, 0, 0);
        }
        __syncthreads();

        for (int ct = 0; ct < NCT; ++ct) {
            const int cur = ct & 1;
            if (ct + 1 < NCT) {
                #pragma unroll
                for (int i = 0; i < 4; ++i) {
                    int ch = wave * 4 + i;
                    const short* gp = whlq + (((size_t)((ct + 1) * 16 + ch)) << 9) + lane * 8;
                    __builtin_amdgcn_global_load_lds(
                        (const __attribute__((address_space(1))) void*)gp,
                        (__attribute__((address_space(3))) void*)&lds_b[cur ^ 1][ch][0], 16, 0, 0);
                }
            }
            float wq = wsq_lds[ct * 16 + n];
            f32x4 acc[2][2];
            #pragma unroll
            for (int a = 0; a < 2; ++a)
                #pragma unroll
                for (int b = 0; b < 2; ++b) acc[a][b] = (f32x4){0.f, 0.f, 0.f, 0.f};
            #pragma unroll
            for (int ks = 0; ks < 8; ++ks) {
                bf16x8 bh = *(const bf16x8*)&lds_b[cur][ks * 2 + 0][lane * 8];
                bf16x8 bl = *(const bf16x8*)&lds_b[cur][ks * 2 + 1][lane * 8];
                const int p = ks & 1;
                acc[0][p] = __builtin_amdgcn_mfma_f32_16x16x32_bf16(ah[0][ks], bh, acc[0][p], 0, 0, 0);
                acc[1][p] = __builtin_amdgcn_mfma_f32_16x16x32_bf16(ah[1][ks], bh, acc[1][p], 0, 0, 0);
                acc[0][p] = __builtin_amdgcn_mfma_f32_16x16x32_bf16(al[0][ks], bh, acc[0][p], 0, 0, 0);
                acc[1][p] = __builtin_amdgcn_mfma_f32_16x16x32_bf16(al[1][ks], bh, acc[1][p], 0, 0, 0);
                acc[0][p] = __builtin_amdgcn_mfma_f32_16x16x32_bf16(ah[0][ks], bl, acc[0][p], 0, 0, 0);
                acc[1][p] = __builtin_amdgcn_mfma_f32_16x16x32_bf16(ah[1][ks], bl, acc[1][p], 0, 0, 0);
            }
            int cg = ct * 16 + n;
            #pragma unroll
            for (int rt = 0; rt < 2; ++rt) {
                #pragma unroll
                for (int rg = 0; rg < 4; ++rg) {
                    float g = acc[rt][0][rg] + acc[rt][1][rg];
                    float d = (sreg[rt][rg] - 2.0f * g) + wq;
                    int s = rt * 4 + rg;
                    if (d < m1[s]) { m2[s] = m1[s]; m1[s] = d; i1[s] = cg; }
                    else if (d < m2[s]) m2[s] = d;
                }
            }
            __syncthreads();   // staged loads drained (compiler waitcnt) + buf swap safe
        }

        // ---- reduce argmin over the 16 lanes of each quad ----
        #pragma unroll
        for (int s = 0; s < 8; ++s) {
            float a1 = m1[s], a2 = m2[s]; int ai = i1[s];
            #pragma unroll
            for (int mask = 1; mask < 16; mask <<= 1) {
                float b1 = __shfl_xor(a1, mask, 64);
                float b2 = __shfl_xor(a2, mask, 64);
                int   bi = __shfl_xor(ai, mask, 64);
                if (b1 < a1 || (b1 == a1 && bi < ai)) { a2 = fminf(b2, a1); a1 = b1; ai = bi; }
                else a2 = fminf(a2, b1);
            }
            if (n == 0) {
                int rr = wave * 32 + (s >> 2) * 16 + kq * 4 + (s & 3);
                rowm1[rr] = a1; rowm2[rr] = a2; rowi1[rr] = ai;
            }
        }
        __syncthreads();
        if (tid < TM) {
            idx_s[tid] = rowi1[tid];
            if (rowm2[tid] - rowm1[tid] <= TAU) {
                int p = atomicAdd(&rk_cnt, 1);
                rk_list[p] = tid;
            }
        }
        __syncthreads();

        // ---- exact numpy-chain recheck for near-tied rows ----
        {
            int ncheck = rk_cnt;
            for (int f = 0; f < ncheck; ++f) {
                int r = rk_list[f];
                if (tid < 64)
                    ((float4*)rrow_s)[tid] =
                        ((const float4*)(resd_g + (((size_t)(row0 + r)) << 8)))[tid];
                __syncthreads();
                float Sr = Srow[r];
                float accv[8];
                #pragma unroll
                for (int j = 0; j < 8; ++j) accv[j] = 0.f;
                const float* wp = Wk + ((size_t)tid * 8) * EDIM;
                for (int k = 0; k < EDIM; ++k) {
                    float rv = rrow_s[k];
                    #pragma unroll
                    for (int j = 0; j < 8; ++j)
                        accv[j] = fmaf(rv, wp[j * EDIM + k], accv[j]);
                }
                float bm = FLT_MAX; int bi = 0;
                #pragma unroll
                for (int j = 0; j < 8; ++j) {
                    int c = tid * 8 + j;
                    float d = (Sr - 2.0f * accv[j]) + wsq_lds[c];
                    if (d < bm) { bm = d; bi = c; }
                }
                red_f[tid] = bm; red_i[tid] = bi;
                __syncthreads();
                for (int off = 128; off > 0; off >>= 1) {
                    if (tid < off) {
                        float v = red_f[tid + off]; int ii = red_i[tid + off];
                        if (v < red_f[tid] || (v == red_f[tid] && ii < red_i[tid])) {
                            red_f[tid] = v; red_i[tid] = ii;
                        }
                    }
                    __syncthreads();
                }
                if (tid == 0) idx_s[r] = red_i[0];
                __syncthreads();
            }
        }

        if (tid < TM)
            out[IDX_OFF + (size_t)(row0 + tid) * N_Q + q] = (float)idx_s[tid];
        __syncthreads();

        // ---- residual update (plain fp32 sub, numpy elementwise) + loss ----
        {
            const int d = tid;
            for (int r = 0; r < TM; ++r) {
                float w = Wk[(((size_t)idx_s[r]) << 8) + d];
                float* rp = resd_g + (((size_t)(row0 + r)) << 8) + d;
                float nv = *rp - w;
                *rp = nv;
                lsum = fmaf(nv, nv, lsum);
            }
        }
    }

    __syncthreads();
    // z_q = z - residual_final
    for (int i = tid; i < TM * 64; i += NTHREADS) {
        int r = i >> 6, c = i & 63;
        float4 zv = ((const float4*)z)[(((size_t)(row0 + r)) << 6) + c];
        float4 rv = ((const float4*)resd_g)[(((size_t)(row0 + r)) << 6) + c];
        float4 o = {zv.x - rv.x, zv.y - rv.y, zv.z - rv.z, zv.w - rv.w};
        ((float4*)out)[(((size_t)(row0 + r)) << 6) + c] = o;
    }
    #pragma unroll
    for (int off = 32; off > 0; off >>= 1) lsum += __shfl_down(lsum, off, 64);
    if (lane == 0) wavesum[wave] = lsum;
    __syncthreads();
    if (tid == 0)
        loss_partial[blockIdx.x] = wavesum[0] + wavesum[1] + wavesum[2] + wavesum[3];
}

__global__ __launch_bounds__(256) void loss_reduce(const float* __restrict__ partial,
                                                   float* __restrict__ out) {
    __shared__ float sh[256];
    int t = threadIdx.x;
    sh[t] = partial[t];
    __syncthreads();
    for (int off = 128; off > 0; off >>= 1) {
        if (t < off) sh[t] += sh[t + off];
        __syncthreads();
    }
    if (t == 0)
        out[LOSS_OFF] = sh[0] * (1.25f / ((float)N_Q * (float)NROWS * (float)EDIM));
}

extern "C" void kernel_launch(void* const* d_in, const int* in_sizes, int n_in,
                              void* d_out, int out_size, void* d_ws, size_t ws_size,
                              hipStream_t stream) {
    const float* z = (const float*)d_in[0];   // [16,2048,256]
    const float* W = (const float*)d_in[1];   // [4,2048,256]
    float* out = (float*)d_out;

    // ws layout (bytes): wsq32 [0,32K) | partial [32K,33K) | whl [64K, 64K+8M) | resd [+32M)
    float* wsq32   = (float*)d_ws;
    float* partial = (float*)((char*)d_ws + 32768);
    short* whl     = (short*)((char*)d_ws + 65536);
    float* resd    = (float*)((char*)d_ws + 65536 + 8388608);

    hipLaunchKernelGGL(wsq_kernel, dim3(NE * N_Q / 4), dim3(NTHREADS), 0, stream, W, wsq32);
    hipLaunchKernelGGL(whl_kernel, dim3(1024), dim3(NTHREADS), 0, stream, W, whl);
    hipLaunchKernelGGL(rvq_main, dim3(NROWS / TM), dim3(NTHREADS), 0, stream,
                       z, W, wsq32, whl, resd, out, partial);
    hipLaunchKernelGGL(loss_reduce, dim3(1), dim3(NTHREADS), 0, stream, partial, out);
}

// Round 6
// 1002.828 us; speedup vs baseline: 2.4496x; 1.3356x over previous
//
#include <hip/hip_runtime.h>
#include <cstdint>
#include <math.h>
#include <float.h>

// Problem constants
#define N_Q   4
#define NROWS 32768
#define EDIM  256
#define NE    2048
#define NCT   128          // code tiles of 16 codes
#define TM    64           // rows per block (4 waves x 16 rows) -> grid 512, 2-3 blocks/CU
#define NTHREADS 256

// Output layout: z_q | loss | indices (fp32)
#define ZQ_SIZE  (NROWS * EDIM)
#define LOSS_OFF ZQ_SIZE
#define IDX_OFF  (ZQ_SIZE + 1)

// approx(bf16x3-MFMA) vs numpy-chain dist error: rms ~1e-5, worst ~1e-4; 10x margin
#define TAU 1e-3f

typedef __attribute__((ext_vector_type(8))) __bf16 bf16x8;
typedef __attribute__((ext_vector_type(4))) float  f32x4;

union BF8 { unsigned short u[8]; bf16x8 v; };

__device__ __forceinline__ unsigned short f2bf_rne(float f) {
    unsigned int u = __float_as_uint(f);
    unsigned int r = (u + 0x7fffu + ((u >> 16) & 1u)) >> 16;
    return (unsigned short)r;
}
__device__ __forceinline__ float bf2f(unsigned short s) {
    return __uint_as_float(((unsigned int)s) << 16);
}

// ---- numpy pairwise fp32 sum-of-squares emulation (256 = 128 + 128) ----
__device__ __forceinline__ float np_block128_sq(const float* __restrict__ p) {
    #pragma clang fp contract(off)
    float r[8];
    #pragma unroll
    for (int j = 0; j < 8; ++j) { float v = p[j]; r[j] = v * v; }
    for (int i = 8; i < 128; i += 8) {
        #pragma unroll
        for (int j = 0; j < 8; ++j) { float v = p[i + j]; float sq = v * v; r[j] = r[j] + sq; }
    }
    return ((r[0] + r[1]) + (r[2] + r[3])) + ((r[4] + r[5]) + (r[6] + r[7]));
}

__global__ __launch_bounds__(256) void wsq_kernel(const float* __restrict__ W,
                                                  float* __restrict__ wsq32) {
    __shared__ float rowbuf[4][EDIM];
    int wv   = threadIdx.x >> 6;
    int row  = blockIdx.x * 4 + wv;
    int lane = threadIdx.x & 63;
    float4 v = ((const float4*)(W + (size_t)row * EDIM))[lane];
    *(float4*)&rowbuf[wv][lane * 4] = v;
    __syncthreads();
    if (lane == 0) {
        float a = np_block128_sq(rowbuf[wv]);
        float b = np_block128_sq(rowbuf[wv] + 128);
        wsq32[row] = a + b;
    }
}

// Pre-split W into bf16 hi/lo, swizzled into MFMA B-frag blocks:
// whl layout (shorts): chunk = ((q*128+ct)*8+ks)*2+h ; within chunk: lane*8+j
// value = bfpart( W[q][ct*16 + (lane&15)][ks*32 + (lane>>4)*8 + j] )
__global__ __launch_bounds__(256) void whl_kernel(const float* __restrict__ W,
                                                  short* __restrict__ whl) {
    int gid  = blockIdx.x * 256 + threadIdx.x;
    int lane = gid & 63;
    int grp  = gid >> 6;                 // (q*128+ct)*8+ks, 4096 total
    int ks   = grp & 7;
    int ctq  = grp >> 3;                 // q*128+ct
    int n = lane & 15, kq = lane >> 4;
    const float* src = W + (((size_t)(ctq * 16 + n)) << 8) + ks * 32 + kq * 8;
    float4 p0 = *(const float4*)src;
    float4 p1 = *(const float4*)(src + 4);
    float v[8] = {p0.x, p0.y, p0.z, p0.w, p1.x, p1.y, p1.z, p1.w};
    BF8 h, l;
    #pragma unroll
    for (int j = 0; j < 8; ++j) {
        float f = v[j];
        unsigned short hb = f2bf_rne(f);
        h.u[j] = hb;
        l.u[j] = f2bf_rne(f - bf2f(hb));
    }
    size_t base = ((size_t)grp << 10) + lane * 8;   // shorts
    *(bf16x8*)(whl + base)       = h.v;
    *(bf16x8*)(whl + base + 512) = l.v;
}

__global__ __launch_bounds__(256, 2) void rvq_main(
    const float* __restrict__ z, const float* __restrict__ W,
    const float* __restrict__ wsq32, const short* __restrict__ whl,
    float* __restrict__ resd_g, float* __restrict__ out,
    float* __restrict__ loss_partial)
{
    __shared__ __align__(16) short lds_b[2][16][512];  // 32 KB B-frag dbuf
    __shared__ float wsq_lds[NE];                      // 8 KB
    __shared__ float Srow[TM];
    __shared__ float rowm1[TM], rowm2[TM];
    __shared__ int   rowi1[TM], idx_s[TM];
    __shared__ int   rk_cnt, rk_list[TM];
    __shared__ float rrow_s[EDIM];
    __shared__ float red_f[NTHREADS];
    __shared__ int   red_i[NTHREADS];
    __shared__ float wavesum[4];

    const int tid  = threadIdx.x;
    const int wave = tid >> 6;
    const int lane = tid & 63;
    const int n    = lane & 15;
    const int kq   = lane >> 4;
    const int row0 = blockIdx.x * TM;
    const int rowg = row0 + wave * 16;   // this wave's 16 rows

    // init: copy z -> residual (own rows only)
    for (int i = tid; i < TM * 64; i += NTHREADS) {
        int r = i >> 6, c = i & 63;
        ((float4*)resd_g)[(((size_t)(row0 + r)) << 6) + c] =
            ((const float4*)z)[(((size_t)(row0 + r)) << 6) + c];
    }

    float lsum = 0.f;

    for (int q = 0; q < N_Q; ++q) {
        const float* Wk   = W + (size_t)q * NE * EDIM;
        const short* whlq = whl + (size_t)q * NCT * 16 * 512;

        __syncthreads();   // residual stable; lds_b / wsq_lds free
        if (tid == 0) rk_cnt = 0;
        for (int i = tid; i < NE / 4; i += NTHREADS)
            ((float4*)wsq_lds)[i] = ((const float4*)(wsq32 + q * NE))[i];
        if (tid < 2 * TM) {
            int r = tid >> 1, half = tid & 1;
            float s = np_block128_sq(resd_g + (((size_t)(row0 + r)) << 8) + half * 128);
            float s2 = __shfl_xor(s, 1, 64);
            if (half == 0) Srow[r] = s + s2;   // block0 + block1 (numpy order)
        }
        __syncthreads();

        // ---- A-frag conversion: 16 rows/wave, 8 k-steps, hi/lo resident ----
        bf16x8 ah[8], al[8];
        #pragma unroll
        for (int ks = 0; ks < 8; ++ks) {
            const float* rp = resd_g + (((size_t)(rowg + n)) << 8) + ks * 32 + kq * 8;
            float4 p0 = *(const float4*)rp;
            float4 p1 = *(const float4*)(rp + 4);
            float v[8] = {p0.x, p0.y, p0.z, p0.w, p1.x, p1.y, p1.z, p1.w};
            BF8 h, l;
            #pragma unroll
            for (int j = 0; j < 8; ++j) {
                float f = v[j];
                unsigned short hb = f2bf_rne(f);
                h.u[j] = hb;
                l.u[j] = f2bf_rne(f - bf2f(hb));
            }
            ah[ks] = h.v; al[ks] = l.v;
        }
        float sreg[4];
        #pragma unroll
        for (int rg = 0; rg < 4; ++rg)
            sreg[rg] = Srow[wave * 16 + kq * 4 + rg];

        float m1[4], m2[4]; int i1[4];
        #pragma unroll
        for (int s = 0; s < 4; ++s) { m1[s] = INFINITY; m2[s] = INFINITY; i1[s] = 0; }

        // prologue: stage ct=0 into buf 0 (each wave stages 4 of 16 chunks)
        #pragma unroll
        for (int i = 0; i < 4; ++i) {
            int ch = wave * 4 + i;
            const short* gp = whlq + (((size_t)ch) << 9) + lane * 8;
            __builtin_amdgcn_global_load_lds(
                (const __attribute__((address_space(1))) void*)gp,
                (__attribute__((address_space(3))) void*)&lds_b[0][ch][0], 16, 0, 0);
        }
        __syncthreads();

        for (int ct = 0; ct < NCT; ++ct) {
            const int cur = ct & 1;
            if (ct + 1 < NCT) {
                #pragma unroll
                for (int i = 0; i < 4; ++i) {
                    int ch = wave * 4 + i;
                    const short* gp = whlq + (((size_t)((ct + 1) * 16 + ch)) << 9) + lane * 8;
                    __builtin_amdgcn_global_load_lds(
                        (const __attribute__((address_space(1))) void*)gp,
                        (__attribute__((address_space(3))) void*)&lds_b[cur ^ 1][ch][0], 16, 0, 0);
                }
            }
            float wq = wsq_lds[ct * 16 + n];
            f32x4 acc[4];
            #pragma unroll
            for (int c = 0; c < 4; ++c) acc[c] = (f32x4){0.f, 0.f, 0.f, 0.f};
            #pragma unroll
            for (int ks = 0; ks < 8; ++ks) {
                bf16x8 bh = *(const bf16x8*)&lds_b[cur][ks * 2 + 0][lane * 8];
                bf16x8 bl = *(const bf16x8*)&lds_b[cur][ks * 2 + 1][lane * 8];
                const int c = ks & 3;   // 4 independent chains, depth 6
                acc[c] = __builtin_amdgcn_mfma_f32_16x16x32_bf16(ah[ks], bh, acc[c], 0, 0, 0);
                acc[c] = __builtin_amdgcn_mfma_f32_16x16x32_bf16(al[ks], bh, acc[c], 0, 0, 0);
                acc[c] = __builtin_amdgcn_mfma_f32_16x16x32_bf16(ah[ks], bl, acc[c], 0, 0, 0);
            }
            int cg = ct * 16 + n;
            #pragma unroll
            for (int rg = 0; rg < 4; ++rg) {
                float g = (acc[0][rg] + acc[1][rg]) + (acc[2][rg] + acc[3][rg]);
                float d = (sreg[rg] - 2.0f * g) + wq;
                if (d < m1[rg]) { m2[rg] = m1[rg]; m1[rg] = d; i1[rg] = cg; }
                else if (d < m2[rg]) m2[rg] = d;
            }
            __syncthreads();   // prefetch drained + buf swap safe
        }

        // ---- reduce argmin over the 16 n-lanes of each kq group ----
        #pragma unroll
        for (int s = 0; s < 4; ++s) {
            float a1 = m1[s], a2 = m2[s]; int ai = i1[s];
            #pragma unroll
            for (int mask = 1; mask < 16; mask <<= 1) {
                float b1 = __shfl_xor(a1, mask, 64);
                float b2 = __shfl_xor(a2, mask, 64);
                int   bi = __shfl_xor(ai, mask, 64);
                if (b1 < a1 || (b1 == a1 && bi < ai)) { a2 = fminf(b2, a1); a1 = b1; ai = bi; }
                else a2 = fminf(a2, b1);
            }
            if (n == 0) {
                int rr = wave * 16 + kq * 4 + s;
                rowm1[rr] = a1; rowm2[rr] = a2; rowi1[rr] = ai;
            }
        }
        __syncthreads();
        if (tid < TM) {
            idx_s[tid] = rowi1[tid];
            if (rowm2[tid] - rowm1[tid] <= TAU) {
                int p = atomicAdd(&rk_cnt, 1);
                rk_list[p] = tid;
            }
        }
        __syncthreads();

        // ---- exact numpy-chain recheck for near-tied rows (rare) ----
        {
            int ncheck = rk_cnt;
            for (int f = 0; f < ncheck; ++f) {
                int r = rk_list[f];
                if (tid < 64)
                    ((float4*)rrow_s)[tid] =
                        ((const float4*)(resd_g + (((size_t)(row0 + r)) << 8)))[tid];
                __syncthreads();
                float Sr = Srow[r];
                float accv[8];
                #pragma unroll
                for (int j = 0; j < 8; ++j) accv[j] = 0.f;
                const float* wp = Wk + ((size_t)tid * 8) * EDIM;
                for (int kb = 0; kb < 64; ++kb) {
                    float4 rv = *(const float4*)&rrow_s[kb * 4];
                    #pragma unroll
                    for (int j = 0; j < 8; ++j) {
                        float4 wv = *(const float4*)(wp + j * EDIM + kb * 4);
                        // ascending-k sequential chain (numpy/OpenBLAS order)
                        accv[j] = fmaf(rv.x, wv.x, accv[j]);
                        accv[j] = fmaf(rv.y, wv.y, accv[j]);
                        accv[j] = fmaf(rv.z, wv.z, accv[j]);
                        accv[j] = fmaf(rv.w, wv.w, accv[j]);
                    }
                }
                float bm = FLT_MAX; int bi = 0;
                #pragma unroll
                for (int j = 0; j < 8; ++j) {
                    int c = tid * 8 + j;
                    float d = (Sr - 2.0f * accv[j]) + wsq_lds[c];
                    if (d < bm) { bm = d; bi = c; }
                }
                red_f[tid] = bm; red_i[tid] = bi;
                __syncthreads();
                for (int off = 128; off > 0; off >>= 1) {
                    if (tid < off) {
                        float v = red_f[tid + off]; int ii = red_i[tid + off];
                        if (v < red_f[tid] || (v == red_f[tid] && ii < red_i[tid])) {
                            red_f[tid] = v; red_i[tid] = ii;
                        }
                    }
                    __syncthreads();
                }
                if (tid == 0) idx_s[r] = red_i[0];
                __syncthreads();
            }
        }

        if (tid < TM)
            out[IDX_OFF + (size_t)(row0 + tid) * N_Q + q] = (float)idx_s[tid];
        __syncthreads();

        // ---- residual update (plain fp32 sub, numpy elementwise) + loss ----
        {
            const int d = tid;
            for (int r = 0; r < TM; ++r) {
                float w = Wk[(((size_t)idx_s[r]) << 8) + d];
                float* rp = resd_g + (((size_t)(row0 + r)) << 8) + d;
                float nv = *rp - w;
                *rp = nv;
                lsum = fmaf(nv, nv, lsum);
            }
        }
    }

    __syncthreads();
    // z_q = z - residual_final
    for (int i = tid; i < TM * 64; i += NTHREADS) {
        int r = i >> 6, c = i & 63;
        float4 zv = ((const float4*)z)[(((size_t)(row0 + r)) << 6) + c];
        float4 rv = ((const float4*)resd_g)[(((size_t)(row0 + r)) << 6) + c];
        float4 o = {zv.x - rv.x, zv.y - rv.y, zv.z - rv.z, zv.w - rv.w};
        ((float4*)out)[(((size_t)(row0 + r)) << 6) + c] = o;
    }
    #pragma unroll
    for (int off = 32; off > 0; off >>= 1) lsum += __shfl_down(lsum, off, 64);
    if (lane == 0) wavesum[wave] = lsum;
    __syncthreads();
    if (tid == 0)
        loss_partial[blockIdx.x] = wavesum[0] + wavesum[1] + wavesum[2] + wavesum[3];
}

__global__ __launch_bounds__(256) void loss_reduce(const float* __restrict__ partial,
                                                   float* __restrict__ out) {
    __shared__ float sh[256];
    int t = threadIdx.x;
    sh[t] = partial[t] + partial[t + 256];
    __syncthreads();
    for (int off = 128; off > 0; off >>= 1) {
        if (t < off) sh[t] += sh[t + off];
        __syncthreads();
    }
    if (t == 0)
        out[LOSS_OFF] = sh[0] * (1.25f / ((float)N_Q * (float)NROWS * (float)EDIM));
}

extern "C" void kernel_launch(void* const* d_in, const int* in_sizes, int n_in,
                              void* d_out, int out_size, void* d_ws, size_t ws_size,
                              hipStream_t stream) {
    const float* z = (const float*)d_in[0];   // [16,2048,256]
    const float* W = (const float*)d_in[1];   // [4,2048,256]
    float* out = (float*)d_out;

    // ws layout (bytes): wsq32 [0,32K) | partial [32K,34K) | whl [64K, 64K+8M) | resd [+32M)
    float* wsq32   = (float*)d_ws;
    float* partial = (float*)((char*)d_ws + 32768);
    short* whl     = (short*)((char*)d_ws + 65536);
    float* resd    = (float*)((char*)d_ws + 65536 + 8388608);

    hipLaunchKernelGGL(wsq_kernel, dim3(NE * N_Q / 4), dim3(NTHREADS), 0, stream, W, wsq32);
    hipLaunchKernelGGL(whl_kernel, dim3(1024), dim3(NTHREADS), 0, stream, W, whl);
    hipLaunchKernelGGL(rvq_main, dim3(NROWS / TM), dim3(NTHREADS), 0, stream,
                       z, W, wsq32, whl, resd, out, partial);
    hipLaunchKernelGGL(loss_reduce, dim3(1), dim3(NTHREADS), 0, stream, partial, out);
}

// Round 7
// 890.244 us; speedup vs baseline: 2.7594x; 1.1265x over previous
//
#include <hip/hip_runtime.h>
#include <cstdint>
#include <math.h>
#include <float.h>

// Problem constants
#define N_Q   4
#define NROWS 32768
#define EDIM  256
#define NE    2048
#define NCT_H 64           // code tiles (16 codes) per half
#define TM    64           // rows per block; grid 512 -> 2 blocks/CU
#define NTHREADS 256

// Output layout: z_q | loss | indices (fp32)
#define ZQ_SIZE  (NROWS * EDIM)
#define LOSS_OFF ZQ_SIZE
#define IDX_OFF  (ZQ_SIZE + 1)

// approx(bf16x3-MFMA) vs numpy-chain dist error: rms ~1e-5, worst ~1e-4; 10x margin
#define TAU 1e-3f

typedef __attribute__((ext_vector_type(8))) __bf16 bf16x8;
typedef __attribute__((ext_vector_type(4))) float  f32x4;

union BF8 { unsigned short u[8]; bf16x8 v; };

__device__ __forceinline__ unsigned short f2bf_rne(float f) {
    unsigned int u = __float_as_uint(f);
    unsigned int r = (u + 0x7fffu + ((u >> 16) & 1u)) >> 16;
    return (unsigned short)r;
}
__device__ __forceinline__ float bf2f(unsigned short s) {
    return __uint_as_float(((unsigned int)s) << 16);
}

// ---- numpy pairwise fp32 sum-of-squares emulation (256 = 128 + 128) ----
__device__ __forceinline__ float np_block128_sq(const float* __restrict__ p) {
    #pragma clang fp contract(off)
    float r[8];
    #pragma unroll
    for (int j = 0; j < 8; ++j) { float v = p[j]; r[j] = v * v; }
    for (int i = 8; i < 128; i += 8) {
        #pragma unroll
        for (int j = 0; j < 8; ++j) { float v = p[i + j]; float sq = v * v; r[j] = r[j] + sq; }
    }
    return ((r[0] + r[1]) + (r[2] + r[3])) + ((r[4] + r[5]) + (r[6] + r[7]));
}

__global__ __launch_bounds__(256) void wsq_kernel(const float* __restrict__ W,
                                                  float* __restrict__ wsq32) {
    __shared__ float rowbuf[4][EDIM];
    int wv   = threadIdx.x >> 6;
    int row  = blockIdx.x * 4 + (threadIdx.x >> 6);
    int lane = threadIdx.x & 63;
    float4 v = ((const float4*)(W + (size_t)row * EDIM))[lane];
    *(float4*)&rowbuf[wv][lane * 4] = v;
    __syncthreads();
    if (lane == 0) {
        float a = np_block128_sq(rowbuf[wv]);
        float b = np_block128_sq(rowbuf[wv] + 128);
        wsq32[row] = a + b;
    }
}

// Pre-split W into bf16 hi/lo, swizzled into MFMA B-frag blocks:
// grp = (q*128 + ct_global)*8 + ks ; hi at grp<<10, lo at +512 (shorts)
// value = bfpart( W[q][ct_global*16 + (lane&15)][ks*32 + (lane>>4)*8 + j] )
__global__ __launch_bounds__(256) void whl_kernel(const float* __restrict__ W,
                                                  short* __restrict__ whl) {
    int gid  = blockIdx.x * 256 + threadIdx.x;
    int lane = gid & 63;
    int grp  = gid >> 6;                 // 4096 total
    int ctq  = grp >> 3;
    int ks   = grp & 7;
    int n = lane & 15, kq = lane >> 4;
    const float* src = W + (((size_t)(ctq * 16 + n)) << 8) + ks * 32 + kq * 8;
    float4 p0 = *(const float4*)src;
    float4 p1 = *(const float4*)(src + 4);
    float v[8] = {p0.x, p0.y, p0.z, p0.w, p1.x, p1.y, p1.z, p1.w};
    BF8 h, l;
    #pragma unroll
    for (int j = 0; j < 8; ++j) {
        float f = v[j];
        unsigned short hb = f2bf_rne(f);
        h.u[j] = hb;
        l.u[j] = f2bf_rne(f - bf2f(hb));
    }
    size_t base = ((size_t)grp << 10) + lane * 8;   // shorts
    *(bf16x8*)(whl + base)       = h.v;
    *(bf16x8*)(whl + base + 512) = l.v;
}

__global__ __launch_bounds__(256, 2) void rvq_main(
    const float* __restrict__ z, const float* __restrict__ W,
    const float* __restrict__ wsq32, const short* __restrict__ whl,
    float* __restrict__ resd_g, float* __restrict__ out,
    float* __restrict__ loss_partial)
{
    __shared__ __align__(16) short lds_b[2][2][8][512];  // 32 KB: [kp-buf][half][ksl*2+hl][512]
    __shared__ float Srow[TM];
    __shared__ float rm1[2][TM], rm2[2][TM];
    __shared__ int   ri1[2][TM];
    __shared__ int   idx_s[TM];
    __shared__ int   rk_cnt, rk_list[TM];
    __shared__ float rrow_s[EDIM];
    __shared__ float red_f[NTHREADS];
    __shared__ int   red_i[NTHREADS];
    __shared__ float wavesum[4];

    const int tid  = threadIdx.x;
    const int wave = tid >> 6;
    const int lane = tid & 63;
    const int n    = lane & 15;
    const int kq   = lane >> 4;
    const int half = wave >> 1;      // code half (0: codes 0..1023, 1: 1024..2047)
    const int rsel = wave & 1;       // row half (0: rows 0..31, 1: 32..63)
    const int row0 = blockIdx.x * TM;
    const int rowg = row0 + rsel * 32;

    // init: copy z -> residual (own rows only)
    for (int i = tid; i < TM * 64; i += NTHREADS) {
        int r = i >> 6, c = i & 63;
        ((float4*)resd_g)[(((size_t)(row0 + r)) << 6) + c] =
            ((const float4*)z)[(((size_t)(row0 + r)) << 6) + c];
    }

    float lsum = 0.f;

    for (int q = 0; q < N_Q; ++q) {
        const float* Wk     = W + (size_t)q * NE * EDIM;
        const float* wsqk   = wsq32 + q * NE;
        const short* whlq   = whl + ((size_t)q << 20);   // q * 128*8*1024 shorts

        __syncthreads();   // residual stable; lds_b free
        if (tid == 0) rk_cnt = 0;
        if (tid < 2 * TM) {
            int r = tid >> 1, hf = tid & 1;
            float s = np_block128_sq(resd_g + (((size_t)(row0 + r)) << 8) + hf * 128);
            float s2 = __shfl_xor(s, 1, 64);
            if (hf == 0) Srow[r] = s + s2;   // block0 + block1 (numpy order)
        }
        __syncthreads();

        // ---- A-frag conversion: 32 rows/wave (2 tiles), 8 k-steps, hi/lo ----
        bf16x8 ah[2][8], al[2][8];
        #pragma unroll
        for (int t = 0; t < 2; ++t) {
            #pragma unroll
            for (int ks = 0; ks < 8; ++ks) {
                const float* rp = resd_g + (((size_t)(rowg + t * 16 + n)) << 8) + ks * 32 + kq * 8;
                float4 p0 = *(const float4*)rp;
                float4 p1 = *(const float4*)(rp + 4);
                float v[8] = {p0.x, p0.y, p0.z, p0.w, p1.x, p1.y, p1.z, p1.w};
                BF8 h, l;
                #pragma unroll
                for (int j = 0; j < 8; ++j) {
                    float f = v[j];
                    unsigned short hb = f2bf_rne(f);
                    h.u[j] = hb;
                    l.u[j] = f2bf_rne(f - bf2f(hb));
                }
                ah[t][ks] = h.v; al[t][ks] = l.v;
            }
        }
        float sreg[2][4];
        #pragma unroll
        for (int t = 0; t < 2; ++t)
            #pragma unroll
            for (int rg = 0; rg < 4; ++rg)
                sreg[t][rg] = Srow[rsel * 32 + t * 16 + kq * 4 + rg];

        float m1[8], m2[8]; int i1[8];
        #pragma unroll
        for (int s = 0; s < 8; ++s) { m1[s] = INFINITY; m2[s] = INFINITY; i1[s] = 0; }

        // staging: wave w stages its 2 grp-chunks (half = w>>1, ksl = 2*(w&1)+j)
        auto stage = [&](int buf, int ct, int kp) {
            #pragma unroll
            for (int j = 0; j < 2; ++j) {
                int ksl = (wave & 1) * 2 + j;
                size_t grp = ((size_t)((wave >> 1) * 64 + ct) << 3) + kp * 4 + ksl;
                const short* gp = whlq + (grp << 10) + lane * 8;
                __builtin_amdgcn_global_load_lds(
                    (const __attribute__((address_space(1))) void*)gp,
                    (__attribute__((address_space(3))) void*)&lds_b[buf][wave >> 1][ksl * 2][0],
                    16, 0, 0);
                __builtin_amdgcn_global_load_lds(
                    (const __attribute__((address_space(1))) void*)(gp + 512),
                    (__attribute__((address_space(3))) void*)&lds_b[buf][wave >> 1][ksl * 2 + 1][0],
                    16, 0, 0);
            }
        };

        f32x4 acc[2][2];
        // prologue: stage (ct=0, kp=0) into buf 0
        stage(0, 0, 0);
        __syncthreads();

        for (int ct = 0; ct < NCT_H; ++ct) {
            // issue wq load early (consumed at fold)
            float wq = wsqk[(half * 64 + ct) * 16 + n];

            // ---- phase A: compute buf0 (ks 0..3); stage kp=1 into buf1 ----
            stage(1, ct, 1);
            #pragma unroll
            for (int t = 0; t < 2; ++t)
                #pragma unroll
                for (int c = 0; c < 2; ++c) acc[t][c] = (f32x4){0.f, 0.f, 0.f, 0.f};
            #pragma unroll
            for (int ksl = 0; ksl < 4; ++ksl) {
                bf16x8 bh = *(const bf16x8*)&lds_b[0][half][ksl * 2 + 0][lane * 8];
                bf16x8 bl = *(const bf16x8*)&lds_b[0][half][ksl * 2 + 1][lane * 8];
                const int ks = ksl, c = ksl & 1;
                acc[0][c] = __builtin_amdgcn_mfma_f32_16x16x32_bf16(ah[0][ks], bh, acc[0][c], 0, 0, 0);
                acc[0][c] = __builtin_amdgcn_mfma_f32_16x16x32_bf16(al[0][ks], bh, acc[0][c], 0, 0, 0);
                acc[0][c] = __builtin_amdgcn_mfma_f32_16x16x32_bf16(ah[0][ks], bl, acc[0][c], 0, 0, 0);
                acc[1][c] = __builtin_amdgcn_mfma_f32_16x16x32_bf16(ah[1][ks], bh, acc[1][c], 0, 0, 0);
                acc[1][c] = __builtin_amdgcn_mfma_f32_16x16x32_bf16(al[1][ks], bh, acc[1][c], 0, 0, 0);
                acc[1][c] = __builtin_amdgcn_mfma_f32_16x16x32_bf16(ah[1][ks], bl, acc[1][c], 0, 0, 0);
            }
            __syncthreads();   // buf1 staged+drained; everyone done with buf0

            // ---- phase B: compute buf1 (ks 4..7); stage next ct kp=0 into buf0 ----
            if (ct + 1 < NCT_H) stage(0, ct + 1, 0);
            #pragma unroll
            for (int ksl = 0; ksl < 4; ++ksl) {
                bf16x8 bh = *(const bf16x8*)&lds_b[1][half][ksl * 2 + 0][lane * 8];
                bf16x8 bl = *(const bf16x8*)&lds_b[1][half][ksl * 2 + 1][lane * 8];
                const int ks = 4 + ksl, c = ksl & 1;
                acc[0][c] = __builtin_amdgcn_mfma_f32_16x16x32_bf16(ah[0][ks], bh, acc[0][c], 0, 0, 0);
                acc[0][c] = __builtin_amdgcn_mfma_f32_16x16x32_bf16(al[0][ks], bh, acc[0][c], 0, 0, 0);
                acc[0][c] = __builtin_amdgcn_mfma_f32_16x16x32_bf16(ah[0][ks], bl, acc[0][c], 0, 0, 0);
                acc[1][c] = __builtin_amdgcn_mfma_f32_16x16x32_bf16(ah[1][ks], bh, acc[1][c], 0, 0, 0);
                acc[1][c] = __builtin_amdgcn_mfma_f32_16x16x32_bf16(al[1][ks], bh, acc[1][c], 0, 0, 0);
                acc[1][c] = __builtin_amdgcn_mfma_f32_16x16x32_bf16(ah[1][ks], bl, acc[1][c], 0, 0, 0);
            }

            // ---- fold: d = fp32(S - 2G) + Wsq, numpy rounding order ----
            int cg = (half * 64 + ct) * 16 + n;
            #pragma unroll
            for (int t = 0; t < 2; ++t) {
                #pragma unroll
                for (int rg = 0; rg < 4; ++rg) {
                    float g = acc[t][0][rg] + acc[t][1][rg];
                    float d = fmaf(-2.0f, g, sreg[t][rg]) + wq;
                    int s = t * 4 + rg;
                    if (d < m1[s]) { m2[s] = m1[s]; m1[s] = d; i1[s] = cg; }
                    else if (d < m2[s]) m2[s] = d;
                }
            }
            __syncthreads();   // buf0 staged+drained; everyone done with buf1
        }

        // ---- reduce argmin over the 16 n-lanes ----
        #pragma unroll
        for (int s = 0; s < 8; ++s) {
            float a1 = m1[s], a2 = m2[s]; int ai = i1[s];
            #pragma unroll
            for (int mask = 1; mask < 16; mask <<= 1) {
                float b1 = __shfl_xor(a1, mask, 64);
                float b2 = __shfl_xor(a2, mask, 64);
                int   bi = __shfl_xor(ai, mask, 64);
                if (b1 < a1 || (b1 == a1 && bi < ai)) { a2 = fminf(b2, a1); a1 = b1; ai = bi; }
                else a2 = fminf(a2, b1);
            }
            if (n == 0) {
                int rr = rsel * 32 + (s >> 2) * 16 + kq * 4 + (s & 3);
                rm1[half][rr] = a1; rm2[half][rr] = a2; ri1[half][rr] = ai;
            }
        }
        __syncthreads();

        // ---- merge halves (ties -> half0 = lower index = numpy first-occurrence) ----
        if (tid < TM) {
            float a1 = rm1[0][tid], a2 = rm2[0][tid]; int ai = ri1[0][tid];
            float b1 = rm1[1][tid], b2 = rm2[1][tid]; int bi = ri1[1][tid];
            float m1v, m2v; int iv;
            if (b1 < a1) { m1v = b1; iv = bi; m2v = fminf(b2, a1); }
            else         { m1v = a1; iv = ai; m2v = fminf(a2, b1); }
            idx_s[tid] = iv;
            if (m2v - m1v <= TAU) {
                int p = atomicAdd(&rk_cnt, 1);
                rk_list[p] = tid;
            }
        }
        __syncthreads();

        // ---- exact numpy-chain recheck for near-tied rows (rare) ----
        {
            int ncheck = rk_cnt;
            for (int f = 0; f < ncheck; ++f) {
                int r = rk_list[f];
                if (tid < 64)
                    ((float4*)rrow_s)[tid] =
                        ((const float4*)(resd_g + (((size_t)(row0 + r)) << 8)))[tid];
                __syncthreads();
                float Sr = Srow[r];
                float accv[8];
                #pragma unroll
                for (int j = 0; j < 8; ++j) accv[j] = 0.f;
                const float* wp = Wk + ((size_t)tid * 8) * EDIM;
                for (int kb = 0; kb < 64; ++kb) {
                    float4 rv = *(const float4*)&rrow_s[kb * 4];
                    #pragma unroll
                    for (int j = 0; j < 8; ++j) {
                        float4 wv = *(const float4*)(wp + j * EDIM + kb * 4);
                        accv[j] = fmaf(rv.x, wv.x, accv[j]);
                        accv[j] = fmaf(rv.y, wv.y, accv[j]);
                        accv[j] = fmaf(rv.z, wv.z, accv[j]);
                        accv[j] = fmaf(rv.w, wv.w, accv[j]);
                    }
                }
                float bm = FLT_MAX; int bi = 0;
                #pragma unroll
                for (int j = 0; j < 8; ++j) {
                    int c = tid * 8 + j;
                    float d = fmaf(-2.0f, accv[j], Sr) + wsqk[c];
                    if (d < bm) { bm = d; bi = c; }
                }
                red_f[tid] = bm; red_i[tid] = bi;
                __syncthreads();
                for (int off = 128; off > 0; off >>= 1) {
                    if (tid < off) {
                        float v = red_f[tid + off]; int ii = red_i[tid + off];
                        if (v < red_f[tid] || (v == red_f[tid] && ii < red_i[tid])) {
                            red_f[tid] = v; red_i[tid] = ii;
                        }
                    }
                    __syncthreads();
                }
                if (tid == 0) idx_s[r] = red_i[0];
                __syncthreads();
            }
        }

        if (tid < TM)
            out[IDX_OFF + (size_t)(row0 + tid) * N_Q + q] = (float)idx_s[tid];
        __syncthreads();

        // ---- residual update (plain fp32 sub, numpy elementwise) + loss ----
        {
            const int d = tid;
            for (int r = 0; r < TM; ++r) {
                float w = Wk[(((size_t)idx_s[r]) << 8) + d];
                float* rp = resd_g + (((size_t)(row0 + r)) << 8) + d;
                float nv = *rp - w;
                *rp = nv;
                lsum = fmaf(nv, nv, lsum);
            }
        }
    }

    __syncthreads();
    // z_q = z - residual_final
    for (int i = tid; i < TM * 64; i += NTHREADS) {
        int r = i >> 6, c = i & 63;
        float4 zv = ((const float4*)z)[(((size_t)(row0 + r)) << 6) + c];
        float4 rv = ((const float4*)resd_g)[(((size_t)(row0 + r)) << 6) + c];
        float4 o = {zv.x - rv.x, zv.y - rv.y, zv.z - rv.z, zv.w - rv.w};
        ((float4*)out)[(((size_t)(row0 + r)) << 6) + c] = o;
    }
    #pragma unroll
    for (int off = 32; off > 0; off >>= 1) lsum += __shfl_down(lsum, off, 64);
    if (lane == 0) wavesum[wave] = lsum;
    __syncthreads();
    if (tid == 0)
        loss_partial[blockIdx.x] = wavesum[0] + wavesum[1] + wavesum[2] + wavesum[3];
}

__global__ __launch_bounds__(256) void loss_reduce(const float* __restrict__ partial,
                                                   float* __restrict__ out) {
    __shared__ float sh[256];
    int t = threadIdx.x;
    sh[t] = partial[t] + partial[t + 256];
    __syncthreads();
    for (int off = 128; off > 0; off >>= 1) {
        if (t < off) sh[t] += sh[t + off];
        __syncthreads();
    }
    if (t == 0)
        out[LOSS_OFF] = sh[0] * (1.25f / ((float)N_Q * (float)NROWS * (float)EDIM));
}

extern "C" void kernel_launch(void* const* d_in, const int* in_sizes, int n_in,
                              void* d_out, int out_size, void* d_ws, size_t ws_size,
                              hipStream_t stream) {
    const float* z = (const float*)d_in[0];   // [16,2048,256]
    const float* W = (const float*)d_in[1];   // [4,2048,256]
    float* out = (float*)d_out;

    // ws layout (bytes): wsq32 [0,32K) | partial [32K,34K) | whl [64K, 64K+8M) | resd [+32M)
    float* wsq32   = (float*)d_ws;
    float* partial = (float*)((char*)d_ws + 32768);
    short* whl     = (short*)((char*)d_ws + 65536);
    float* resd    = (float*)((char*)d_ws + 65536 + 8388608);

    hipLaunchKernelGGL(wsq_kernel, dim3(NE * N_Q / 4), dim3(NTHREADS), 0, stream, W, wsq32);
    hipLaunchKernelGGL(whl_kernel, dim3(1024), dim3(NTHREADS), 0, stream, W, whl);
    hipLaunchKernelGGL(rvq_main, dim3(NROWS / TM), dim3(NTHREADS), 0, stream,
                       z, W, wsq32, whl, resd, out, partial);
    hipLaunchKernelGGL(loss_reduce, dim3(1), dim3(NTHREADS), 0, stream, partial, out);
}